// Round 5
// baseline (706.451 us; speedup 1.0000x reference)
//
#include <hip/hip_runtime.h>
#include <stdint.h>

#define V 256
#define H 256
#define CONDD 64
#define WIDTH 64
#define KSTEPS 5
#define BR 64
#define GWMAX 0.05f
// Swizzle for 512B-row LDS tiles: XOR byte bits[7:4] with row bits[3:0].
// A-frag b128 read: granule = (ks*4+lg) ^ lc -> per 16-lane group (fixed lg)
// all 16 granules distinct -> 2 lanes/bank-quad = free.
// b16 sample scatter (r&15 = lg*4+i): lg parity -> bank bit6, lg>>1 -> byte
// bit7 (same bank, diff word) -> 2-way = free.
#define SW(r) (((r) & 15) << 4)
// xS rows are 128B; 8-granule space, XOR row bits[2:0].
#define SWX(r) (((r) & 7) << 4)

typedef __attribute__((ext_vector_type(8))) short s16x8;
typedef __attribute__((ext_vector_type(4))) float f32x4;

__device__ __forceinline__ uint64_t splitmix64(uint64_t x) {
  x += 0x9E3779B97F4A7C15ULL;
  x = (x ^ (x >> 30)) * 0xBF58476D1CE4E5B9ULL;
  x = (x ^ (x >> 27)) * 0x94D049BB133111EBULL;
  return x ^ (x >> 31);
}
__device__ __forceinline__ unsigned short f2bf(float f) {
  uint32_t u = __float_as_uint(f);
  return (unsigned short)((u + 0x7FFFu + ((u >> 16) & 1u)) >> 16);
}
__device__ __forceinline__ float bf2f(unsigned short s) {
  return __uint_as_float(((uint32_t)s) << 16);
}
__device__ __forceinline__ float lcg_u01(uint64_t& s) {
  s = s * 6364136223846793005ULL + 1442695040888963407ULL;
  return (float)(uint32_t)(s >> 40) * (1.0f / 16777216.0f);
}
__device__ __forceinline__ float softplusf(float x) {
  return fmaxf(x, 0.0f) + log1pf(expf(-fabsf(x)));
}

// ---------------- merged prep kernel (1 launch) ---------------------------
// blocks [0,256): pack W -> Wp_hi/Wp_lo/WTp_hi (MFMA B-frag order, 16x16x32:
//   frag f=(ks*16+nt): lane l holds B[k=ks*32+(l>>4)*8+j][n=nt*16+(l&15)]).
// blocks [256,576): pack fc2 similarly (K=64 -> 2 ks, 80 n-tiles).
// block 576: Wsum + out zero-init.
__global__ void k_prep(const float* __restrict__ W, const float* __restrict__ fc2_w,
                       unsigned short* __restrict__ Wp_hi, unsigned short* __restrict__ Wp_lo,
                       unsigned short* __restrict__ WTp_hi, unsigned short* __restrict__ fc2p,
                       float* __restrict__ Wsum, float* __restrict__ out) {
  int bid = blockIdx.x;
  if (bid < 256) {
    int idx = bid * 256 + threadIdx.x;  // 65536
    int j = idx & 7, l = (idx >> 3) & 63, nt = (idx >> 9) & 15, ks = idx >> 13;
    int kk = ks * 32 + (l >> 4) * 8 + j;
    int n = nt * 16 + (l & 15);
    float wv = W[(size_t)kk * H + n];           // B = W (k=v, n=h)
    unsigned short hi = f2bf(wv);
    Wp_hi[idx] = hi;
    Wp_lo[idx] = f2bf(wv - bf2f(hi));
    WTp_hi[idx] = f2bf(W[(size_t)n * H + kk]);  // B = W^T (k=h, n=v)
  } else if (bid < 576) {
    int idx = (bid - 256) * 256 + threadIdx.x;  // 81920
    int j = idx & 7, l = (idx >> 3) & 63;
    int f = idx >> 9;  // 0..159
    int ks = f / 80, nt = f % 80;
    fc2p[idx] = f2bf(fc2_w[(size_t)(nt * 16 + (l & 15)) * WIDTH + ks * 32 + (l >> 4) * 8 + j]);
  } else {
    int h = threadIdx.x;
    float s = 0.f;
    for (int v = 0; v < V; ++v) s += W[(size_t)v * H + h];
    Wsum[h] = s;
    if (h == 0) out[0] = 0.0f;  // d_out is poisoned 0xAA before every launch
  }
}

// ---------------- MFMA tile pass (A from swizzled LDS, B from global/L2) --
// wave w owns all 4 row-tiles and cols [w*32, w*32+32) (n-tiles 2w, 2w+1).
__device__ __forceinline__ void mm_pass_lds(const char* srcL, const unsigned short* __restrict__ Wp,
                                            int w, int lc, int lg, f32x4 acc[4][2]) {
#pragma unroll
  for (int ks = 0; ks < 8; ++ks) {
    s16x8 af[4];
#pragma unroll
    for (int rt = 0; rt < 4; ++rt) {
      int r = rt * 16 + lc;
      af[rt] = *(const s16x8*)(srcL + r * 512 + ((ks * 64 + lg * 16) ^ SW(r)));
    }
#pragma unroll
    for (int n = 0; n < 2; ++n) {
      int f = ks * 16 + 2 * w + n;
      s16x8 bf = *(const s16x8*)(Wp + ((size_t)f * 64 + lg * 16 + lc) * 8);
#pragma unroll
      for (int rt = 0; rt < 4; ++rt)
        acc[rt][n] = __builtin_amdgcn_mfma_f32_16x16x32_bf16(af[rt], bf, acc[rt][n], 0, 0, 0);
    }
  }
}

// one fc2 output slice into acc[4][2]
__device__ __forceinline__ void fc2_slice(const s16x8 afx[2][4],
                                          const unsigned short* __restrict__ fc2p,
                                          int w, int l, int slice, f32x4 acc[4][2]) {
#pragma unroll
  for (int rt = 0; rt < 4; ++rt)
#pragma unroll
    for (int n = 0; n < 2; ++n) acc[rt][n] = (f32x4){0.f, 0.f, 0.f, 0.f};
#pragma unroll
  for (int ks = 0; ks < 2; ++ks)
#pragma unroll
    for (int n = 0; n < 2; ++n) {
      int f = ks * 80 + slice * 16 + 2 * w + n;
      s16x8 bf = *(const s16x8*)(fc2p + ((size_t)f * 64 + l) * 8);
#pragma unroll
      for (int rt = 0; rt < 4; ++rt)
        acc[rt][n] = __builtin_amdgcn_mfma_f32_16x16x32_bf16(afx[ks][rt], bf, acc[rt][n], 0, 0, 0);
    }
}

// ---------------- fused main kernel --------------------------------------
__global__ __launch_bounds__(512, 1) void rbm_mfma(
    const float* __restrict__ v_data, const float* __restrict__ cond,
    const float* __restrict__ bvec, const float* __restrict__ cvec,
    const float* __restrict__ fc1_w, const float* __restrict__ fc1_b,
    const float* __restrict__ fc2_b, const unsigned short* __restrict__ Wp_hi,
    const unsigned short* __restrict__ Wp_lo, const unsigned short* __restrict__ WTp_hi,
    const unsigned short* __restrict__ fc2p, const float* __restrict__ Wsum,
    float* __restrict__ out, int Btot, int nnoise) {
  const int tid = threadIdx.x;
  const int w = tid >> 6, l = tid & 63, lc = l & 15, lg = l >> 4;
  const int row0 = blockIdx.x * BR;

  __shared__ unsigned short vmL[BR * 256];  // v_model bf16, swizzled 512B rows
  __shared__ unsigned short hwL[BR * 256];  // h*wsc; early: cond+x overlay; late: v_data
  __shared__ float red[BR][8];

  uint64_t rs = splitmix64(((uint64_t)(blockIdx.x * 512 + tid) << 1) | 1ULL);

  if (tid < BR * 8) ((float*)red)[tid] = 0.0f;

  float* condS = (float*)hwL;            // [64][68] f32 = 17408 B
  char* xS = (char*)hwL + 64 * 68 * 4;   // 64 rows x 128 B bf16 (SWX swizzle)

  // ---- stage cond (coalesced)
#pragma unroll
  for (int s = 0; s < 8; ++s) {
    int e = s * 512 + tid, r = e >> 6, k = e & 63;
    condS[r * 68 + k] = cond[(size_t)(row0 + r) * CONDD + k];
  }
  // ---- stage v_model (bf16, swizzled; first nnoise rows = Bernoulli(0.5))
#pragma unroll
  for (int s = 0; s < 4; ++s) {
    int unit = s * 512 + tid;
    int r = unit >> 5, c0 = (unit & 31) * 8;
    int g = row0 + r;
    s16x8 pk;
    if (g < nnoise) {
      rs = rs * 6364136223846793005ULL + 1442695040888963407ULL;
      uint32_t bits = (uint32_t)(rs >> 32);
#pragma unroll
      for (int j = 0; j < 8; ++j) pk[j] = (short)(((bits >> j) & 1u) ? 0x3F80 : 0);
    } else {
      const float* src = v_data + (size_t)g * 256 + c0;
      float4 a = *(const float4*)src, b = *(const float4*)(src + 4);
      pk[0] = (short)f2bf(a.x); pk[1] = (short)f2bf(a.y);
      pk[2] = (short)f2bf(a.z); pk[3] = (short)f2bf(a.w);
      pk[4] = (short)f2bf(b.x); pk[5] = (short)f2bf(b.y);
      pk[6] = (short)f2bf(b.z); pk[7] = (short)f2bf(b.w);
    }
    *(s16x8*)((char*)vmL + r * 512 + ((c0 * 2) ^ SW(r))) = pk;
  }
  __syncthreads();

  // ---- fc1: x = tanh(cond @ fc1_w^T + fc1_b), bf16 into xS (A-frag layout)
  {
    int r = tid >> 3, j0 = (tid & 7) * 8;
    float a8[8];
#pragma unroll
    for (int j = 0; j < 8; ++j) a8[j] = fc1_b[j0 + j];
    for (int k = 0; k < CONDD; ++k) {
      float cv = condS[r * 68 + k];
#pragma unroll
      for (int j = 0; j < 8; ++j)
        a8[j] = fmaf(cv, fc1_w[(size_t)(j0 + j) * CONDD + k], a8[j]);
    }
    s16x8 xp;
#pragma unroll
    for (int j = 0; j < 8; ++j) xp[j] = (short)f2bf(tanhf(a8[j]));
    *(s16x8*)(xS + r * 128 + ((j0 * 2) ^ SWX(r))) = xp;
  }
  __syncthreads();

  // ---- fc2 via MFMA, 5 sequential slices (keeps live regs low)
  float bm[4][2][4], cm[4][2][4], ws[4][2][4];
  {
    s16x8 afx[2][4];
#pragma unroll
    for (int ks = 0; ks < 2; ++ks)
#pragma unroll
      for (int rt = 0; rt < 4; ++rt) {
        int r = rt * 16 + lc;
        afx[ks][rt] = *(const s16x8*)(xS + r * 128 + (((ks * 32 + lg * 8) * 2) ^ SWX(r)));
      }
    f32x4 acc[4][2];
    fc2_slice(afx, fc2p, w, l, 0, acc);  // gb
#pragma unroll
    for (int rt = 0; rt < 4; ++rt)
#pragma unroll
      for (int n = 0; n < 2; ++n)
#pragma unroll
        for (int i = 0; i < 4; ++i) bm[rt][n][i] = acc[rt][n][i];
    fc2_slice(afx, fc2p, w, l, 1, acc);  // bb
#pragma unroll
    for (int n = 0; n < 2; ++n) {
      int col = w * 32 + n * 16 + lc;
      float fb0 = fc2_b[col], fb1 = fc2_b[V + col], bv = bvec[col];
#pragma unroll
      for (int rt = 0; rt < 4; ++rt)
#pragma unroll
        for (int i = 0; i < 4; ++i)
          bm[rt][n][i] = fmaf(1.0f + (bm[rt][n][i] + fb0), bv, acc[rt][n][i] + fb1);
    }
    fc2_slice(afx, fc2p, w, l, 2, acc);  // gc
#pragma unroll
    for (int rt = 0; rt < 4; ++rt)
#pragma unroll
      for (int n = 0; n < 2; ++n)
#pragma unroll
        for (int i = 0; i < 4; ++i) cm[rt][n][i] = acc[rt][n][i];
    fc2_slice(afx, fc2p, w, l, 3, acc);  // bc
#pragma unroll
    for (int n = 0; n < 2; ++n) {
      int col = w * 32 + n * 16 + lc;
      float fb2 = fc2_b[2 * V + col], fb3 = fc2_b[2 * V + H + col];
      float cv = cvec[col];
#pragma unroll
      for (int rt = 0; rt < 4; ++rt)
#pragma unroll
        for (int i = 0; i < 4; ++i)
          cm[rt][n][i] = fmaf(1.0f + (cm[rt][n][i] + fb2), cv, acc[rt][n][i] + fb3);
    }
    fc2_slice(afx, fc2p, w, l, 4, acc);  // gw
#pragma unroll
    for (int n = 0; n < 2; ++n) {
      int col = w * 32 + n * 16 + lc;
      float fb4 = fc2_b[2 * V + 2 * H + col];
#pragma unroll
      for (int rt = 0; rt < 4; ++rt)
#pragma unroll
        for (int i = 0; i < 4; ++i)
          ws[rt][n][i] = 1.0f + GWMAX * tanhf(acc[rt][n][i] + fb4);
    }
  }
  // Sb = sum_v bm[r][v]
#pragma unroll
  for (int rt = 0; rt < 4; ++rt)
#pragma unroll
    for (int i = 0; i < 4; ++i) {
      float s = bm[rt][0][i] + bm[rt][1][i];
      s += __shfl_xor(s, 1); s += __shfl_xor(s, 2);
      s += __shfl_xor(s, 4); s += __shfl_xor(s, 8);
      if (lc == 0) atomicAdd(&red[rt * 16 + lg * 4 + i][6], s);
    }
  __syncthreads();  // x/cond reads done; hwL free for h-samples

  // ---- Gibbs chain; final v-samples kept as register bitmask
  uint32_t vbits = 0;
  for (int step = 0; step < KSTEPS; ++step) {
    f32x4 acc[4][2];
#pragma unroll
    for (int rt = 0; rt < 4; ++rt)
#pragma unroll
      for (int n = 0; n < 2; ++n) acc[rt][n] = (f32x4){0.f, 0.f, 0.f, 0.f};
    mm_pass_lds((const char*)vmL, Wp_hi, w, lc, lg, acc);
#pragma unroll
    for (int rt = 0; rt < 4; ++rt)
#pragma unroll
      for (int n = 0; n < 2; ++n)
#pragma unroll
        for (int i = 0; i < 4; ++i) {
          float act = fmaf(acc[rt][n][i], ws[rt][n][i], cm[rt][n][i]);
          float e = __expf(-act);
          float u = lcg_u01(rs);
          unsigned short hv = (fmaf(u, e, u) < 1.0f) ? f2bf(ws[rt][n][i]) : (unsigned short)0;
          int r = rt * 16 + lg * 4 + i, c = w * 32 + n * 16 + lc;
          *(unsigned short*)((char*)hwL + r * 512 + ((c * 2) ^ SW(r))) = hv;
        }
    __syncthreads();
#pragma unroll
    for (int rt = 0; rt < 4; ++rt)
#pragma unroll
      for (int n = 0; n < 2; ++n) acc[rt][n] = (f32x4){0.f, 0.f, 0.f, 0.f};
    mm_pass_lds((const char*)hwL, WTp_hi, w, lc, lg, acc);
#pragma unroll
    for (int rt = 0; rt < 4; ++rt)
#pragma unroll
      for (int n = 0; n < 2; ++n)
#pragma unroll
        for (int i = 0; i < 4; ++i) {
          float act = acc[rt][n][i] + bm[rt][n][i];
          float e = __expf(-act);
          float u = lcg_u01(rs);
          int bit = (fmaf(u, e, u) < 1.0f) ? 1 : 0;
          if (step == KSTEPS - 1) vbits |= ((uint32_t)bit << (rt * 8 + n * 4 + i));
          int r = rt * 16 + lg * 4 + i, c = w * 32 + n * 16 + lc;
          *(unsigned short*)((char*)vmL + r * 512 + ((c * 2) ^ SW(r))) =
              bit ? (unsigned short)0x3F80 : (unsigned short)0;
        }
    __syncthreads();
  }

  // ---- stage v_data into hwL (bf16, swizzled) for the FE data pass
#pragma unroll
  for (int s = 0; s < 4; ++s) {
    int unit = s * 512 + tid;
    int r = unit >> 5, c0 = (unit & 31) * 8;
    const float* src = v_data + (size_t)(row0 + r) * 256 + c0;
    float4 a = *(const float4*)src, b = *(const float4*)(src + 4);
    s16x8 pk;
    pk[0] = (short)f2bf(a.x); pk[1] = (short)f2bf(a.y);
    pk[2] = (short)f2bf(a.z); pk[3] = (short)f2bf(a.w);
    pk[4] = (short)f2bf(b.x); pk[5] = (short)f2bf(b.y);
    pk[6] = (short)f2bf(b.z); pk[7] = (short)f2bf(b.w);
    *(s16x8*)((char*)hwL + r * 512 + ((c0 * 2) ^ SW(r))) = pk;
  }
  __syncthreads();

  // ---- free energy (hi+lo W split for accuracy)
  {
    float ws2[2];
    ws2[0] = Wsum[w * 32 + lc];
    ws2[1] = Wsum[w * 32 + 16 + lc];
    f32x4 acc[4][2];

    // model pass (vmL; st from vbits registers)
#pragma unroll
    for (int rt = 0; rt < 4; ++rt)
#pragma unroll
      for (int n = 0; n < 2; ++n) acc[rt][n] = (f32x4){0.f, 0.f, 0.f, 0.f};
    mm_pass_lds((const char*)vmL, Wp_hi, w, lc, lg, acc);
    mm_pass_lds((const char*)vmL, Wp_lo, w, lc, lg, acc);
#pragma unroll
    for (int rt = 0; rt < 4; ++rt)
#pragma unroll
      for (int i = 0; i < 4; ++i) {
        float sv = 0.f, sf = 0.f, st = 0.f;
        int r = rt * 16 + lg * 4 + i;
#pragma unroll
        for (int n = 0; n < 2; ++n) {
          float vw = acc[rt][n][i];
          sv += softplusf(fmaf(vw, ws[rt][n][i], cm[rt][n][i]));
          sf += softplusf(fmaf(ws2[n] - vw, ws[rt][n][i], cm[rt][n][i]));
          if ((vbits >> (rt * 8 + n * 4 + i)) & 1u) st += bm[rt][n][i];
        }
        sv += __shfl_xor(sv, 1); sv += __shfl_xor(sv, 2); sv += __shfl_xor(sv, 4); sv += __shfl_xor(sv, 8);
        sf += __shfl_xor(sf, 1); sf += __shfl_xor(sf, 2); sf += __shfl_xor(sf, 4); sf += __shfl_xor(sf, 8);
        st += __shfl_xor(st, 1); st += __shfl_xor(st, 2); st += __shfl_xor(st, 4); st += __shfl_xor(st, 8);
        if (lc == 0) {
          atomicAdd(&red[r][3], sv);
          atomicAdd(&red[r][4], sf);
          atomicAdd(&red[r][5], st);
        }
      }

    // data pass (hwL = staged v_data)
#pragma unroll
    for (int rt = 0; rt < 4; ++rt)
#pragma unroll
      for (int n = 0; n < 2; ++n) acc[rt][n] = (f32x4){0.f, 0.f, 0.f, 0.f};
    mm_pass_lds((const char*)hwL, Wp_hi, w, lc, lg, acc);
    mm_pass_lds((const char*)hwL, Wp_lo, w, lc, lg, acc);
#pragma unroll
    for (int rt = 0; rt < 4; ++rt)
#pragma unroll
      for (int i = 0; i < 4; ++i) {
        float sv = 0.f, sf = 0.f, st = 0.f;
        int r = rt * 16 + lg * 4 + i;
#pragma unroll
        for (int n = 0; n < 2; ++n) {
          float vw = acc[rt][n][i];
          sv += softplusf(fmaf(vw, ws[rt][n][i], cm[rt][n][i]));
          sf += softplusf(fmaf(ws2[n] - vw, ws[rt][n][i], cm[rt][n][i]));
          int c = w * 32 + n * 16 + lc;
          float xv = bf2f(*(const unsigned short*)((const char*)hwL + r * 512 + ((c * 2) ^ SW(r))));
          st = fmaf(xv, bm[rt][n][i], st);
        }
        sv += __shfl_xor(sv, 1); sv += __shfl_xor(sv, 2); sv += __shfl_xor(sv, 4); sv += __shfl_xor(sv, 8);
        sf += __shfl_xor(sf, 1); sf += __shfl_xor(sf, 2); sf += __shfl_xor(sf, 4); sf += __shfl_xor(sf, 8);
        st += __shfl_xor(st, 1); st += __shfl_xor(st, 2); st += __shfl_xor(st, 4); st += __shfl_xor(st, 8);
        if (lc == 0) {
          atomicAdd(&red[r][0], sv);
          atomicAdd(&red[r][1], sf);
          atomicAdd(&red[r][2], st);
        }
      }
  }
  __syncthreads();

  if (tid < 64) {
    int r = tid;
    float a_d = red[r][2] + red[r][0];
    float b_d = (red[r][6] - red[r][2]) + red[r][1];
    float fe_d = -(fmaxf(a_d, b_d) + log1pf(expf(-fabsf(a_d - b_d))));
    float a_m = red[r][5] + red[r][3];
    float b_m = (red[r][6] - red[r][5]) + red[r][4];
    float fe_m = -(fmaxf(a_m, b_m) + log1pf(expf(-fabsf(a_m - b_m))));
    float d = fe_d - fe_m;
#pragma unroll
    for (int m = 1; m < 64; m <<= 1) d += __shfl_xor(d, m);
    if (tid == 0) atomicAdd(out, d * (1.0f / (float)Btot));
  }
}

// ---------------- launch --------------------------------------------------
extern "C" void kernel_launch(void* const* d_in, const int* in_sizes, int n_in,
                              void* d_out, int out_size, void* d_ws, size_t ws_size,
                              hipStream_t stream) {
  const float* v_data = (const float*)d_in[0];
  const float* cond = (const float*)d_in[1];
  const float* W = (const float*)d_in[2];
  const float* bvec = (const float*)d_in[3];
  const float* cvec = (const float*)d_in[4];
  const float* fc1_w = (const float*)d_in[5];
  const float* fc1_b = (const float*)d_in[6];
  const float* fc2_w = (const float*)d_in[7];
  const float* fc2_b = (const float*)d_in[8];
  float* out = (float*)d_out;

  int Btot = in_sizes[0] / V;              // 32768
  int nnoise = (int)((double)Btot * 0.1);  // 3276

  // ws (shorts): Wp_hi[65536] | Wp_lo[65536] | WTp_hi[65536] | fc2p[81920] | Wsum f32[256]
  unsigned short* Wp_hi = (unsigned short*)d_ws;
  unsigned short* Wp_lo = Wp_hi + 65536;
  unsigned short* WTp_hi = Wp_lo + 65536;
  unsigned short* fc2p = WTp_hi + 65536;
  float* Wsum = (float*)(fc2p + 81920);

  k_prep<<<577, 256, 0, stream>>>(W, fc2_w, Wp_hi, Wp_lo, WTp_hi, fc2p, Wsum, out);
  rbm_mfma<<<Btot / BR, 512, 0, stream>>>(v_data, cond, bvec, cvec, fc1_w, fc1_b, fc2_b,
                                          Wp_hi, Wp_lo, WTp_hi, fc2p, Wsum, out, Btot, nnoise);
}

// Round 6
// 655.693 us; speedup vs baseline: 1.0774x; 1.0774x over previous
//
#include <hip/hip_runtime.h>
#include <stdint.h>

#define V 256
#define H 256
#define CONDD 64
#define WIDTH 64
#define KSTEPS 5
#define BR 64
#define GWMAX 0.05f
// Swizzle for 512B-row LDS tiles: XOR byte bits[7:4] with row bits[3:0].
// Verified round 5: SQ_LDS_BANK_CONFLICT 9.5M -> 32K (free).
#define SW(r) (((r) & 15) << 4)
// xS rows are 128B; 8-granule space, XOR row bits[2:0].
#define SWX(r) (((r) & 7) << 4)

typedef __attribute__((ext_vector_type(8))) short s16x8;
typedef __attribute__((ext_vector_type(4))) float f32x4;

__device__ __forceinline__ uint64_t splitmix64(uint64_t x) {
  x += 0x9E3779B97F4A7C15ULL;
  x = (x ^ (x >> 30)) * 0xBF58476D1CE4E5B9ULL;
  x = (x ^ (x >> 27)) * 0x94D049BB133111EBULL;
  return x ^ (x >> 31);
}
__device__ __forceinline__ unsigned short f2bf(float f) {
  uint32_t u = __float_as_uint(f);
  return (unsigned short)((u + 0x7FFFu + ((u >> 16) & 1u)) >> 16);
}
__device__ __forceinline__ float bf2f(unsigned short s) {
  return __uint_as_float(((uint32_t)s) << 16);
}
__device__ __forceinline__ uint32_t pack2(float lo, float hi) {
  return (uint32_t)f2bf(lo) | ((uint32_t)f2bf(hi) << 16);
}
__device__ __forceinline__ float unpk_lo(uint32_t u) { return bf2f((unsigned short)(u & 0xFFFFu)); }
__device__ __forceinline__ float unpk_hi(uint32_t u) { return bf2f((unsigned short)(u >> 16)); }
__device__ __forceinline__ float lcg_u01(uint64_t& s) {
  s = s * 6364136223846793005ULL + 1442695040888963407ULL;
  return (float)(uint32_t)(s >> 40) * (1.0f / 16777216.0f);
}
__device__ __forceinline__ float softplusf(float x) {
  return fmaxf(x, 0.0f) + log1pf(expf(-fabsf(x)));
}

// ---------------- merged prep kernel (1 launch) ---------------------------
__global__ void k_prep(const float* __restrict__ W, const float* __restrict__ fc2_w,
                       unsigned short* __restrict__ Wp_hi, unsigned short* __restrict__ Wp_lo,
                       unsigned short* __restrict__ WTp_hi, unsigned short* __restrict__ fc2p,
                       float* __restrict__ Wsum, float* __restrict__ out) {
  int bid = blockIdx.x;
  if (bid < 256) {
    int idx = bid * 256 + threadIdx.x;  // 65536
    int j = idx & 7, l = (idx >> 3) & 63, nt = (idx >> 9) & 15, ks = idx >> 13;
    int kk = ks * 32 + (l >> 4) * 8 + j;
    int n = nt * 16 + (l & 15);
    float wv = W[(size_t)kk * H + n];           // B = W (k=v, n=h)
    unsigned short hi = f2bf(wv);
    Wp_hi[idx] = hi;
    Wp_lo[idx] = f2bf(wv - bf2f(hi));
    WTp_hi[idx] = f2bf(W[(size_t)n * H + kk]);  // B = W^T (k=h, n=v)
  } else if (bid < 576) {
    int idx = (bid - 256) * 256 + threadIdx.x;  // 81920
    int j = idx & 7, l = (idx >> 3) & 63;
    int f = idx >> 9;  // 0..159
    int ks = f / 80, nt = f % 80;
    fc2p[idx] = f2bf(fc2_w[(size_t)(nt * 16 + (l & 15)) * WIDTH + ks * 32 + (l >> 4) * 8 + j]);
  } else {
    int h = threadIdx.x;
    float s = 0.f;
    for (int v = 0; v < V; ++v) s += W[(size_t)v * H + h];
    Wsum[h] = s;
    if (h == 0) out[0] = 0.0f;  // d_out is poisoned 0xAA before every launch
  }
}

// ---------------- half MFMA pass: 2 row-tiles {rt0, rt0+1} ----------------
// acc[2][2] = 16 VGPRs (vs 32 for the full pass) -> fits the 128-VGPR budget.
__device__ __forceinline__ void mm_pass_half(const char* srcL,
                                             const unsigned short* __restrict__ Wp,
                                             int w, int lc, int lg, int rt0, f32x4 acc[2][2]) {
#pragma unroll
  for (int ks = 0; ks < 8; ++ks) {
    s16x8 af[2];
#pragma unroll
    for (int q = 0; q < 2; ++q) {
      int r = (rt0 + q) * 16 + lc;
      af[q] = *(const s16x8*)(srcL + r * 512 + ((ks * 64 + lg * 16) ^ SW(r)));
    }
#pragma unroll
    for (int n = 0; n < 2; ++n) {
      int f = ks * 16 + 2 * w + n;
      s16x8 bf = *(const s16x8*)(Wp + ((size_t)f * 64 + lg * 16 + lc) * 8);
#pragma unroll
      for (int q = 0; q < 2; ++q)
        acc[q][n] = __builtin_amdgcn_mfma_f32_16x16x32_bf16(af[q], bf, acc[q][n], 0, 0, 0);
    }
  }
}

// one fc2 output slice, 2 row-tiles
__device__ __forceinline__ void fc2_slice_half(const s16x8 afx[2][2],
                                               const unsigned short* __restrict__ fc2p,
                                               int w, int l, int slice, f32x4 acc[2][2]) {
#pragma unroll
  for (int q = 0; q < 2; ++q)
#pragma unroll
    for (int n = 0; n < 2; ++n) acc[q][n] = (f32x4){0.f, 0.f, 0.f, 0.f};
#pragma unroll
  for (int ks = 0; ks < 2; ++ks)
#pragma unroll
    for (int n = 0; n < 2; ++n) {
      int f = ks * 80 + slice * 16 + 2 * w + n;
      s16x8 bf = *(const s16x8*)(fc2p + ((size_t)f * 64 + l) * 8);
#pragma unroll
      for (int q = 0; q < 2; ++q)
        acc[q][n] = __builtin_amdgcn_mfma_f32_16x16x32_bf16(afx[ks][q], bf, acc[q][n], 0, 0, 0);
    }
}

// ---------------- fused main kernel --------------------------------------
__global__ __launch_bounds__(512) __attribute__((amdgpu_waves_per_eu(2)))
void rbm_mfma(
    const float* __restrict__ v_data, const float* __restrict__ cond,
    const float* __restrict__ bvec, const float* __restrict__ cvec,
    const float* __restrict__ fc1_w, const float* __restrict__ fc1_b,
    const float* __restrict__ fc2_b, const unsigned short* __restrict__ Wp_hi,
    const unsigned short* __restrict__ Wp_lo, const unsigned short* __restrict__ WTp_hi,
    const unsigned short* __restrict__ fc2p, const float* __restrict__ Wsum,
    float* __restrict__ out, int Btot, int nnoise) {
  const int tid = threadIdx.x;
  const int w = tid >> 6, l = tid & 63, lc = l & 15, lg = l >> 4;
  const int row0 = blockIdx.x * BR;

  __shared__ unsigned short vmL[BR * 256];  // v_model bf16, swizzled 512B rows
  __shared__ unsigned short hwL[BR * 256];  // h*wsc; early: cond+x overlay; late: v_data
  __shared__ float red[BR][8];

  uint64_t rs = splitmix64(((uint64_t)(blockIdx.x * 512 + tid) << 1) | 1ULL);

  ((float*)red)[tid] = 0.0f;  // 512 = BR*8

  float* condS = (float*)hwL;            // [64][68] f32 = 17408 B
  char* xS = (char*)hwL + 64 * 68 * 4;   // 64 rows x 128 B bf16 (SWX swizzle)

  // ---- stage cond (coalesced)
#pragma unroll
  for (int s = 0; s < 8; ++s) {
    int e = s * 512 + tid, r = e >> 6, k = e & 63;
    condS[r * 68 + k] = cond[(size_t)(row0 + r) * CONDD + k];
  }
  // ---- stage v_model (bf16, swizzled; first nnoise rows = Bernoulli(0.5))
#pragma unroll
  for (int s = 0; s < 4; ++s) {
    int unit = s * 512 + tid;
    int r = unit >> 5, c0 = (unit & 31) * 8;
    int g = row0 + r;
    s16x8 pk;
    if (g < nnoise) {
      rs = rs * 6364136223846793005ULL + 1442695040888963407ULL;
      uint32_t bits = (uint32_t)(rs >> 32);
#pragma unroll
      for (int j = 0; j < 8; ++j) pk[j] = (short)(((bits >> j) & 1u) ? 0x3F80 : 0);
    } else {
      const float* src = v_data + (size_t)g * 256 + c0;
      float4 a = *(const float4*)src, b = *(const float4*)(src + 4);
      pk[0] = (short)f2bf(a.x); pk[1] = (short)f2bf(a.y);
      pk[2] = (short)f2bf(a.z); pk[3] = (short)f2bf(a.w);
      pk[4] = (short)f2bf(b.x); pk[5] = (short)f2bf(b.y);
      pk[6] = (short)f2bf(b.z); pk[7] = (short)f2bf(b.w);
    }
    *(s16x8*)((char*)vmL + r * 512 + ((c0 * 2) ^ SW(r))) = pk;
  }
  __syncthreads();

  // ---- fc1: x = tanh(cond @ fc1_w^T + fc1_b), bf16 into xS (A-frag layout)
  {
    int r = tid >> 3, j0 = (tid & 7) * 8;
    float a8[8];
#pragma unroll
    for (int j = 0; j < 8; ++j) a8[j] = fc1_b[j0 + j];
    for (int k = 0; k < CONDD; ++k) {
      float cv = condS[r * 68 + k];
#pragma unroll
      for (int j = 0; j < 8; ++j)
        a8[j] = fmaf(cv, fc1_w[(size_t)(j0 + j) * CONDD + k], a8[j]);
    }
    s16x8 xp;
#pragma unroll
    for (int j = 0; j < 8; ++j) xp[j] = (short)f2bf(tanhf(a8[j]));
    *(s16x8*)(xS + r * 128 + ((j0 * 2) ^ SWX(r))) = xp;
  }
  __syncthreads();

  // ---- fc2 via MFMA, bf16-packed params: cmws = (cm | ws<<16), bmp = (bm_n0 | bm_n1<<16)
  uint32_t cmws[4][2][4];  // 32 VGPRs
  uint32_t bmp[4][4];      // 16 VGPRs
  {
    float fb0[2], fb1[2], fb2[2], fb3[2], fb4[2], bvl[2], cvl[2];
#pragma unroll
    for (int n = 0; n < 2; ++n) {
      int col = w * 32 + n * 16 + lc;
      fb0[n] = fc2_b[col];
      fb1[n] = fc2_b[V + col];
      fb2[n] = fc2_b[2 * V + col];
      fb3[n] = fc2_b[2 * V + H + col];
      fb4[n] = fc2_b[2 * V + 2 * H + col];
      bvl[n] = bvec[col];
      cvl[n] = cvec[col];
    }
#pragma unroll
    for (int half = 0; half < 2; ++half) {
      const int rt0 = half * 2;
      s16x8 afx[2][2];
#pragma unroll
      for (int ks = 0; ks < 2; ++ks)
#pragma unroll
        for (int q = 0; q < 2; ++q) {
          int r = (rt0 + q) * 16 + lc;
          afx[ks][q] = *(const s16x8*)(xS + r * 128 + (((ks * 32 + lg * 8) * 2) ^ SWX(r)));
        }
      f32x4 accA[2][2], accB[2][2];
      fc2_slice_half(afx, fc2p, w, l, 0, accA);  // gb
      fc2_slice_half(afx, fc2p, w, l, 1, accB);  // bb
#pragma unroll
      for (int q = 0; q < 2; ++q)
#pragma unroll
        for (int i = 0; i < 4; ++i)
          bmp[rt0 + q][i] =
              pack2(fmaf(1.0f + (accA[q][0][i] + fb0[0]), bvl[0], accB[q][0][i] + fb1[0]),
                    fmaf(1.0f + (accA[q][1][i] + fb0[1]), bvl[1], accB[q][1][i] + fb1[1]));
      fc2_slice_half(afx, fc2p, w, l, 2, accA);  // gc
      {
        f32x4 accC[2][2];
        fc2_slice_half(afx, fc2p, w, l, 3, accC);  // bc -> cm into accC
#pragma unroll
        for (int q = 0; q < 2; ++q)
#pragma unroll
          for (int n = 0; n < 2; ++n)
#pragma unroll
            for (int i = 0; i < 4; ++i)
              accC[q][n][i] =
                  fmaf(1.0f + (accA[q][n][i] + fb2[n]), cvl[n], accC[q][n][i] + fb3[n]);
        fc2_slice_half(afx, fc2p, w, l, 4, accA);  // gw
#pragma unroll
        for (int q = 0; q < 2; ++q)
#pragma unroll
          for (int n = 0; n < 2; ++n)
#pragma unroll
            for (int i = 0; i < 4; ++i)
              cmws[rt0 + q][n][i] =
                  pack2(accC[q][n][i], 1.0f + GWMAX * tanhf(accA[q][n][i] + fb4[n]));
      }
    }
  }
  // Sb = sum_v bm[r][v]
#pragma unroll
  for (int rt = 0; rt < 4; ++rt)
#pragma unroll
    for (int i = 0; i < 4; ++i) {
      float s = unpk_lo(bmp[rt][i]) + unpk_hi(bmp[rt][i]);
      s += __shfl_xor(s, 1); s += __shfl_xor(s, 2);
      s += __shfl_xor(s, 4); s += __shfl_xor(s, 8);
      if (lc == 0) atomicAdd(&red[rt * 16 + lg * 4 + i][6], s);
    }
  __syncthreads();  // x/cond reads done; hwL free for h-samples

  // ---- Gibbs chain; final v-samples kept as register bitmask
  uint32_t vbits = 0;
  for (int step = 0; step < KSTEPS; ++step) {
#pragma unroll
    for (int half = 0; half < 2; ++half) {
      const int rt0 = half * 2;
      f32x4 acc[2][2];
#pragma unroll
      for (int q = 0; q < 2; ++q)
#pragma unroll
        for (int n = 0; n < 2; ++n) acc[q][n] = (f32x4){0.f, 0.f, 0.f, 0.f};
      mm_pass_half((const char*)vmL, Wp_hi, w, lc, lg, rt0, acc);
#pragma unroll
      for (int q = 0; q < 2; ++q)
#pragma unroll
        for (int n = 0; n < 2; ++n)
#pragma unroll
          for (int i = 0; i < 4; ++i) {
            uint32_t p2 = cmws[rt0 + q][n][i];
            float act = fmaf(acc[q][n][i], unpk_hi(p2), unpk_lo(p2));
            float e = __expf(-act);
            float u = lcg_u01(rs);
            unsigned short hv = (fmaf(u, e, u) < 1.0f) ? (unsigned short)(p2 >> 16)
                                                       : (unsigned short)0;
            int r = (rt0 + q) * 16 + lg * 4 + i, c = w * 32 + n * 16 + lc;
            *(unsigned short*)((char*)hwL + r * 512 + ((c * 2) ^ SW(r))) = hv;
          }
    }
    __syncthreads();
#pragma unroll
    for (int half = 0; half < 2; ++half) {
      const int rt0 = half * 2;
      f32x4 acc[2][2];
#pragma unroll
      for (int q = 0; q < 2; ++q)
#pragma unroll
        for (int n = 0; n < 2; ++n) acc[q][n] = (f32x4){0.f, 0.f, 0.f, 0.f};
      mm_pass_half((const char*)hwL, WTp_hi, w, lc, lg, rt0, acc);
#pragma unroll
      for (int q = 0; q < 2; ++q)
#pragma unroll
        for (int n = 0; n < 2; ++n)
#pragma unroll
          for (int i = 0; i < 4; ++i) {
            float bmv = n ? unpk_hi(bmp[rt0 + q][i]) : unpk_lo(bmp[rt0 + q][i]);
            float act = acc[q][n][i] + bmv;
            float e = __expf(-act);
            float u = lcg_u01(rs);
            int bit = (fmaf(u, e, u) < 1.0f) ? 1 : 0;
            if (step == KSTEPS - 1) vbits |= ((uint32_t)bit << ((rt0 + q) * 8 + n * 4 + i));
            int r = (rt0 + q) * 16 + lg * 4 + i, c = w * 32 + n * 16 + lc;
            *(unsigned short*)((char*)vmL + r * 512 + ((c * 2) ^ SW(r))) =
                bit ? (unsigned short)0x3F80 : (unsigned short)0;
          }
    }
    __syncthreads();
  }

  // ---- stage v_data into hwL (bf16, swizzled) for the FE data pass
#pragma unroll
  for (int s = 0; s < 4; ++s) {
    int unit = s * 512 + tid;
    int r = unit >> 5, c0 = (unit & 31) * 8;
    const float* src = v_data + (size_t)(row0 + r) * 256 + c0;
    float4 a = *(const float4*)src, b = *(const float4*)(src + 4);
    s16x8 pk;
    pk[0] = (short)f2bf(a.x); pk[1] = (short)f2bf(a.y);
    pk[2] = (short)f2bf(a.z); pk[3] = (short)f2bf(a.w);
    pk[4] = (short)f2bf(b.x); pk[5] = (short)f2bf(b.y);
    pk[6] = (short)f2bf(b.z); pk[7] = (short)f2bf(b.w);
    *(s16x8*)((char*)hwL + r * 512 + ((c0 * 2) ^ SW(r))) = pk;
  }
  __syncthreads();

  // ---- free energy (hi+lo W split for accuracy)
  {
    float ws2[2];
    ws2[0] = Wsum[w * 32 + lc];
    ws2[1] = Wsum[w * 32 + 16 + lc];

    // model passes (vmL; st from vbits registers)
#pragma unroll
    for (int half = 0; half < 2; ++half) {
      const int rt0 = half * 2;
      f32x4 acc[2][2];
#pragma unroll
      for (int q = 0; q < 2; ++q)
#pragma unroll
        for (int n = 0; n < 2; ++n) acc[q][n] = (f32x4){0.f, 0.f, 0.f, 0.f};
      mm_pass_half((const char*)vmL, Wp_hi, w, lc, lg, rt0, acc);
      mm_pass_half((const char*)vmL, Wp_lo, w, lc, lg, rt0, acc);
#pragma unroll
      for (int q = 0; q < 2; ++q)
#pragma unroll
        for (int i = 0; i < 4; ++i) {
          float sv = 0.f, sf = 0.f, st = 0.f;
          int r = (rt0 + q) * 16 + lg * 4 + i;
#pragma unroll
          for (int n = 0; n < 2; ++n) {
            uint32_t p2 = cmws[rt0 + q][n][i];
            float cmv = unpk_lo(p2), wsv = unpk_hi(p2);
            float vw = acc[q][n][i];
            sv += softplusf(fmaf(vw, wsv, cmv));
            sf += softplusf(fmaf(ws2[n] - vw, wsv, cmv));
            if ((vbits >> ((rt0 + q) * 8 + n * 4 + i)) & 1u)
              st += n ? unpk_hi(bmp[rt0 + q][i]) : unpk_lo(bmp[rt0 + q][i]);
          }
          sv += __shfl_xor(sv, 1); sv += __shfl_xor(sv, 2); sv += __shfl_xor(sv, 4); sv += __shfl_xor(sv, 8);
          sf += __shfl_xor(sf, 1); sf += __shfl_xor(sf, 2); sf += __shfl_xor(sf, 4); sf += __shfl_xor(sf, 8);
          st += __shfl_xor(st, 1); st += __shfl_xor(st, 2); st += __shfl_xor(st, 4); st += __shfl_xor(st, 8);
          if (lc == 0) {
            atomicAdd(&red[r][3], sv);
            atomicAdd(&red[r][4], sf);
            atomicAdd(&red[r][5], st);
          }
        }
    }

    // data passes (hwL = staged v_data)
#pragma unroll
    for (int half = 0; half < 2; ++half) {
      const int rt0 = half * 2;
      f32x4 acc[2][2];
#pragma unroll
      for (int q = 0; q < 2; ++q)
#pragma unroll
        for (int n = 0; n < 2; ++n) acc[q][n] = (f32x4){0.f, 0.f, 0.f, 0.f};
      mm_pass_half((const char*)hwL, Wp_hi, w, lc, lg, rt0, acc);
      mm_pass_half((const char*)hwL, Wp_lo, w, lc, lg, rt0, acc);
#pragma unroll
      for (int q = 0; q < 2; ++q)
#pragma unroll
        for (int i = 0; i < 4; ++i) {
          float sv = 0.f, sf = 0.f, st = 0.f;
          int r = (rt0 + q) * 16 + lg * 4 + i;
#pragma unroll
          for (int n = 0; n < 2; ++n) {
            uint32_t p2 = cmws[rt0 + q][n][i];
            float cmv = unpk_lo(p2), wsv = unpk_hi(p2);
            float vw = acc[q][n][i];
            sv += softplusf(fmaf(vw, wsv, cmv));
            sf += softplusf(fmaf(ws2[n] - vw, wsv, cmv));
            int c = w * 32 + n * 16 + lc;
            float xv = bf2f(*(const unsigned short*)((const char*)hwL + r * 512 + ((c * 2) ^ SW(r))));
            float bmv = n ? unpk_hi(bmp[rt0 + q][i]) : unpk_lo(bmp[rt0 + q][i]);
            st = fmaf(xv, bmv, st);
          }
          sv += __shfl_xor(sv, 1); sv += __shfl_xor(sv, 2); sv += __shfl_xor(sv, 4); sv += __shfl_xor(sv, 8);
          sf += __shfl_xor(sf, 1); sf += __shfl_xor(sf, 2); sf += __shfl_xor(sf, 4); sf += __shfl_xor(sf, 8);
          st += __shfl_xor(st, 1); st += __shfl_xor(st, 2); st += __shfl_xor(st, 4); st += __shfl_xor(st, 8);
          if (lc == 0) {
            atomicAdd(&red[r][0], sv);
            atomicAdd(&red[r][1], sf);
            atomicAdd(&red[r][2], st);
          }
        }
    }
  }
  __syncthreads();

  if (tid < 64) {
    int r = tid;
    float a_d = red[r][2] + red[r][0];
    float b_d = (red[r][6] - red[r][2]) + red[r][1];
    float fe_d = -(fmaxf(a_d, b_d) + log1pf(expf(-fabsf(a_d - b_d))));
    float a_m = red[r][5] + red[r][3];
    float b_m = (red[r][6] - red[r][5]) + red[r][4];
    float fe_m = -(fmaxf(a_m, b_m) + log1pf(expf(-fabsf(a_m - b_m))));
    float d = fe_d - fe_m;
#pragma unroll
    for (int m = 1; m < 64; m <<= 1) d += __shfl_xor(d, m);
    if (tid == 0) atomicAdd(out, d * (1.0f / (float)Btot));
  }
}

// ---------------- launch --------------------------------------------------
extern "C" void kernel_launch(void* const* d_in, const int* in_sizes, int n_in,
                              void* d_out, int out_size, void* d_ws, size_t ws_size,
                              hipStream_t stream) {
  const float* v_data = (const float*)d_in[0];
  const float* cond = (const float*)d_in[1];
  const float* W = (const float*)d_in[2];
  const float* bvec = (const float*)d_in[3];
  const float* cvec = (const float*)d_in[4];
  const float* fc1_w = (const float*)d_in[5];
  const float* fc1_b = (const float*)d_in[6];
  const float* fc2_w = (const float*)d_in[7];
  const float* fc2_b = (const float*)d_in[8];
  float* out = (float*)d_out;

  int Btot = in_sizes[0] / V;              // 32768
  int nnoise = (int)((double)Btot * 0.1);  // 3276

  // ws (shorts): Wp_hi[65536] | Wp_lo[65536] | WTp_hi[65536] | fc2p[81920] | Wsum f32[256]
  unsigned short* Wp_hi = (unsigned short*)d_ws;
  unsigned short* Wp_lo = Wp_hi + 65536;
  unsigned short* WTp_hi = Wp_lo + 65536;
  unsigned short* fc2p = WTp_hi + 65536;
  float* Wsum = (float*)(fc2p + 81920);

  k_prep<<<577, 256, 0, stream>>>(W, fc2_w, Wp_hi, Wp_lo, WTp_hi, fc2p, Wsum, out);
  rbm_mfma<<<Btot / BR, 512, 0, stream>>>(v_data, cond, bvec, cvec, fc1_w, fc1_b, fc2_b,
                                          Wp_hi, Wp_lo, WTp_hi, fc2p, Wsum, out, Btot, nnoise);
}

// Round 8
// 468.777 us; speedup vs baseline: 1.5070x; 1.3987x over previous
//
#include <hip/hip_runtime.h>
#include <stdint.h>

#define V 256
#define H 256
#define CONDD 64
#define WIDTH 64
#define KSTEPS 5
#define BR 32
#define GWMAX 0.05f
// Swizzle for 512B-row LDS tiles: XOR byte bits[7:4] with row bits[3:0].
// Verified round 5: SQ_LDS_BANK_CONFLICT 9.5M -> 32K (free).
#define SW(r) (((r) & 15) << 4)
// xS rows are 128B; 8-granule space, XOR row bits[2:0].
#define SWX(r) (((r) & 7) << 4)

typedef __attribute__((ext_vector_type(8))) short s16x8;
typedef __attribute__((ext_vector_type(4))) short s16x4;
typedef __attribute__((ext_vector_type(4))) float f32x4;

__device__ __forceinline__ uint64_t splitmix64(uint64_t x) {
  x += 0x9E3779B97F4A7C15ULL;
  x = (x ^ (x >> 30)) * 0xBF58476D1CE4E5B9ULL;
  x = (x ^ (x >> 27)) * 0x94D049BB133111EBULL;
  return x ^ (x >> 31);
}
__device__ __forceinline__ unsigned short f2bf(float f) {
  uint32_t u = __float_as_uint(f);
  return (unsigned short)((u + 0x7FFFu + ((u >> 16) & 1u)) >> 16);
}
__device__ __forceinline__ float bf2f(unsigned short s) {
  return __uint_as_float(((uint32_t)s) << 16);
}
__device__ __forceinline__ uint32_t pack2(float lo, float hi) {
  return (uint32_t)f2bf(lo) | ((uint32_t)f2bf(hi) << 16);
}
__device__ __forceinline__ float unpk_lo(uint32_t u) { return bf2f((unsigned short)(u & 0xFFFFu)); }
__device__ __forceinline__ float unpk_hi(uint32_t u) { return bf2f((unsigned short)(u >> 16)); }
__device__ __forceinline__ float lcg_u01(uint64_t& s) {
  s = s * 6364136223846793005ULL + 1442695040888963407ULL;
  return (float)(uint32_t)(s >> 40) * (1.0f / 16777216.0f);
}
__device__ __forceinline__ float softplusf(float x) {
  return fmaxf(x, 0.0f) + log1pf(expf(-fabsf(x)));
}

// ---------------- merged prep kernel (1 launch) ---------------------------
__global__ void k_prep(const float* __restrict__ W, const float* __restrict__ fc2_w,
                       unsigned short* __restrict__ Wp_hi, unsigned short* __restrict__ Wp_lo,
                       unsigned short* __restrict__ WTp_hi, unsigned short* __restrict__ fc2p,
                       float* __restrict__ Wsum, float* __restrict__ out) {
  int bid = blockIdx.x;
  if (bid < 256) {
    int idx = bid * 256 + threadIdx.x;  // 65536
    int j = idx & 7, l = (idx >> 3) & 63, nt = (idx >> 9) & 15, ks = idx >> 13;
    int kk = ks * 32 + (l >> 4) * 8 + j;
    int n = nt * 16 + (l & 15);
    float wv = W[(size_t)kk * H + n];           // B = W (k=v, n=h)
    unsigned short hi = f2bf(wv);
    Wp_hi[idx] = hi;
    Wp_lo[idx] = f2bf(wv - bf2f(hi));
    WTp_hi[idx] = f2bf(W[(size_t)n * H + kk]);  // B = W^T (k=h, n=v)
  } else if (bid < 576) {
    int idx = (bid - 256) * 256 + threadIdx.x;  // 81920
    int j = idx & 7, l = (idx >> 3) & 63;
    int f = idx >> 9;  // 0..159
    int ks = f / 80, nt = f % 80;
    fc2p[idx] = f2bf(fc2_w[(size_t)(nt * 16 + (l & 15)) * WIDTH + ks * 32 + (l >> 4) * 8 + j]);
  } else {
    int h = threadIdx.x;
    float s = 0.f;
    for (int v = 0; v < V; ++v) s += W[(size_t)v * H + h];
    Wsum[h] = s;
    if (h == 0) out[0] = 0.0f;  // d_out is poisoned 0xAA before every launch
  }
}

// ---------------- MFMA tile pass: 2 row-tiles, 2 n-tiles ------------------
// wave w owns rows [0,32) x cols [w*32, w*32+32); acc[2][2] = 16 VGPRs.
__device__ __forceinline__ void mm_pass(const char* srcL, const unsigned short* __restrict__ Wp,
                                        int w, int lc, int lg, f32x4 acc[2][2]) {
#pragma unroll
  for (int ks = 0; ks < 8; ++ks) {
    s16x8 af[2];
#pragma unroll
    for (int rt = 0; rt < 2; ++rt) {
      int r = rt * 16 + lc;
      af[rt] = *(const s16x8*)(srcL + r * 512 + ((ks * 64 + lg * 16) ^ SW(r)));
    }
#pragma unroll
    for (int n = 0; n < 2; ++n) {
      int f = ks * 16 + 2 * w + n;
      s16x8 bf = *(const s16x8*)(Wp + ((size_t)f * 64 + lg * 16 + lc) * 8);
#pragma unroll
      for (int rt = 0; rt < 2; ++rt)
        acc[rt][n] = __builtin_amdgcn_mfma_f32_16x16x32_bf16(af[rt], bf, acc[rt][n], 0, 0, 0);
    }
  }
}

// one fc2 output slice into acc[2][2]
__device__ __forceinline__ void fc2_slice(const s16x8 afx[2][2],
                                          const unsigned short* __restrict__ fc2p,
                                          int w, int l, int slice, f32x4 acc[2][2]) {
#pragma unroll
  for (int rt = 0; rt < 2; ++rt)
#pragma unroll
    for (int n = 0; n < 2; ++n) acc[rt][n] = (f32x4){0.f, 0.f, 0.f, 0.f};
#pragma unroll
  for (int ks = 0; ks < 2; ++ks)
#pragma unroll
    for (int n = 0; n < 2; ++n) {
      int f = ks * 80 + slice * 16 + 2 * w + n;
      s16x8 bf = *(const s16x8*)(fc2p + ((size_t)f * 64 + l) * 8);
#pragma unroll
      for (int rt = 0; rt < 2; ++rt)
        acc[rt][n] = __builtin_amdgcn_mfma_f32_16x16x32_bf16(afx[ks][rt], bf, acc[rt][n], 0, 0, 0);
    }
}

// ---------------- fused main kernel --------------------------------------
__global__ __launch_bounds__(512) void rbm_mfma(
    const float* __restrict__ v_data, const float* __restrict__ cond,
    const float* __restrict__ bvec, const float* __restrict__ cvec,
    const float* __restrict__ fc1_w, const float* __restrict__ fc1_b,
    const float* __restrict__ fc2_b, const unsigned short* __restrict__ Wp_hi,
    const unsigned short* __restrict__ Wp_lo, const unsigned short* __restrict__ WTp_hi,
    const unsigned short* __restrict__ fc2p, const float* __restrict__ Wsum,
    float* __restrict__ out, int Btot, int nnoise) {
  const int tid = threadIdx.x;
  const int w = tid >> 6, l = tid & 63, lc = l & 15, lg = l >> 4;
  const int row0 = blockIdx.x * BR;

  __shared__ unsigned short vmL[BR * 256];  // v_model bf16, swizzled 512B rows (16 KB)
  __shared__ unsigned short hwL[BR * 256];  // h*wsc; early: cond+x overlay; late: v_data
  __shared__ float red[BR][8];

  uint64_t rs = splitmix64(((uint64_t)(blockIdx.x * 512 + tid) << 1) | 1ULL);

  if (tid < BR * 8) ((float*)red)[tid] = 0.0f;

  float* condS = (float*)hwL;            // [32][68] f32 = 8704 B
  char* xS = (char*)hwL + BR * 68 * 4;   // 32 rows x 128 B bf16 (SWX swizzle)

  // ---- stage cond (coalesced; 32x64 = 2048 floats)
#pragma unroll
  for (int s = 0; s < 4; ++s) {
    int e = s * 512 + tid, r = e >> 6, k = e & 63;
    condS[r * 68 + k] = cond[(size_t)(row0 + r) * CONDD + k];
  }
  // ---- stage v_model (bf16, swizzled; first nnoise rows = Bernoulli(0.5))
#pragma unroll
  for (int s = 0; s < 2; ++s) {
    int unit = s * 512 + tid;
    int r = unit >> 5, c0 = (unit & 31) * 8;
    int g = row0 + r;
    s16x8 pk;
    if (g < nnoise) {
      rs = rs * 6364136223846793005ULL + 1442695040888963407ULL;
      uint32_t bits = (uint32_t)(rs >> 32);
#pragma unroll
      for (int j = 0; j < 8; ++j) pk[j] = (short)(((bits >> j) & 1u) ? 0x3F80 : 0);
    } else {
      const float* src = v_data + (size_t)g * 256 + c0;
      float4 a = *(const float4*)src, b = *(const float4*)(src + 4);
      pk[0] = (short)f2bf(a.x); pk[1] = (short)f2bf(a.y);
      pk[2] = (short)f2bf(a.z); pk[3] = (short)f2bf(a.w);
      pk[4] = (short)f2bf(b.x); pk[5] = (short)f2bf(b.y);
      pk[6] = (short)f2bf(b.z); pk[7] = (short)f2bf(b.w);
    }
    *(s16x8*)((char*)vmL + r * 512 + ((c0 * 2) ^ SW(r))) = pk;
  }
  __syncthreads();

  // ---- fc1: x = tanh(cond @ fc1_w^T + fc1_b); 4 outputs/thread
  {
    int r = tid >> 4, j0 = (tid & 15) * 4;
    float a4[4];
#pragma unroll
    for (int j = 0; j < 4; ++j) a4[j] = fc1_b[j0 + j];
    for (int k = 0; k < CONDD; ++k) {
      float cv = condS[r * 68 + k];
#pragma unroll
      for (int j = 0; j < 4; ++j)
        a4[j] = fmaf(cv, fc1_w[(size_t)(j0 + j) * CONDD + k], a4[j]);
    }
    s16x4 xp;
#pragma unroll
    for (int j = 0; j < 4; ++j) xp[j] = (short)f2bf(tanhf(a4[j]));
    *(s16x4*)(xS + r * 128 + ((j0 * 2) ^ SWX(r))) = xp;
  }
  __syncthreads();

  // ---- fc2 via MFMA, bf16-packed params: cmws = (cm | ws<<16), bmp = (bm_n0 | bm_n1<<16)
  uint32_t cmws[2][2][4];  // 16 VGPRs
  uint32_t bmp[2][4];      // 8 VGPRs
  {
    s16x8 afx[2][2];
#pragma unroll
    for (int ks = 0; ks < 2; ++ks)
#pragma unroll
      for (int rt = 0; rt < 2; ++rt) {
        int r = rt * 16 + lc;
        afx[ks][rt] = *(const s16x8*)(xS + r * 128 + (((ks * 32 + lg * 8) * 2) ^ SWX(r)));
      }
    f32x4 accA[2][2], accB[2][2];
    fc2_slice(afx, fc2p, w, l, 0, accA);  // gb
    fc2_slice(afx, fc2p, w, l, 1, accB);  // bb
#pragma unroll
    for (int rt = 0; rt < 2; ++rt)
#pragma unroll
      for (int i = 0; i < 4; ++i) {
        float b0, b1;
        {
          int c0 = w * 32 + lc, c1 = c0 + 16;
          b0 = fmaf(1.0f + (accA[rt][0][i] + fc2_b[c0]), bvec[c0], accB[rt][0][i] + fc2_b[V + c0]);
          b1 = fmaf(1.0f + (accA[rt][1][i] + fc2_b[c1]), bvec[c1], accB[rt][1][i] + fc2_b[V + c1]);
        }
        bmp[rt][i] = pack2(b0, b1);
      }
    fc2_slice(afx, fc2p, w, l, 2, accA);  // gc
    fc2_slice(afx, fc2p, w, l, 3, accB);  // bc
#pragma unroll
    for (int rt = 0; rt < 2; ++rt)
#pragma unroll
      for (int n = 0; n < 2; ++n) {
        int col = w * 32 + n * 16 + lc;
        float fb2 = fc2_b[2 * V + col], fb3 = fc2_b[2 * V + H + col], cv = cvec[col];
#pragma unroll
        for (int i = 0; i < 4; ++i)
          accB[rt][n][i] = fmaf(1.0f + (accA[rt][n][i] + fb2), cv, accB[rt][n][i] + fb3);
      }
    fc2_slice(afx, fc2p, w, l, 4, accA);  // gw
#pragma unroll
    for (int rt = 0; rt < 2; ++rt)
#pragma unroll
      for (int n = 0; n < 2; ++n) {
        int col = w * 32 + n * 16 + lc;
        float fb4 = fc2_b[2 * V + 2 * H + col];
#pragma unroll
        for (int i = 0; i < 4; ++i)
          cmws[rt][n][i] =
              pack2(accB[rt][n][i], 1.0f + GWMAX * tanhf(accA[rt][n][i] + fb4));
      }
  }
  // Sb = sum_v bm[r][v]
#pragma unroll
  for (int rt = 0; rt < 2; ++rt)
#pragma unroll
    for (int i = 0; i < 4; ++i) {
      float s = unpk_lo(bmp[rt][i]) + unpk_hi(bmp[rt][i]);
      s += __shfl_xor(s, 1); s += __shfl_xor(s, 2);
      s += __shfl_xor(s, 4); s += __shfl_xor(s, 8);
      if (lc == 0) atomicAdd(&red[rt * 16 + lg * 4 + i][6], s);
    }
  __syncthreads();  // x/cond reads done; hwL free for h-samples

  // ---- Gibbs chain; final v-samples kept as register bitmask (16 bits)
  uint32_t vbits = 0;
  for (int step = 0; step < KSTEPS; ++step) {
    f32x4 acc[2][2];
#pragma unroll
    for (int rt = 0; rt < 2; ++rt)
#pragma unroll
      for (int n = 0; n < 2; ++n) acc[rt][n] = (f32x4){0.f, 0.f, 0.f, 0.f};
    mm_pass((const char*)vmL, Wp_hi, w, lc, lg, acc);
#pragma unroll
    for (int rt = 0; rt < 2; ++rt)
#pragma unroll
      for (int n = 0; n < 2; ++n)
#pragma unroll
        for (int i = 0; i < 4; ++i) {
          uint32_t p2 = cmws[rt][n][i];
          float act = fmaf(acc[rt][n][i], unpk_hi(p2), unpk_lo(p2));
          float e = __expf(-act);
          float u = lcg_u01(rs);
          unsigned short hv = (fmaf(u, e, u) < 1.0f) ? (unsigned short)(p2 >> 16)
                                                     : (unsigned short)0;
          int r = rt * 16 + lg * 4 + i, c = w * 32 + n * 16 + lc;
          *(unsigned short*)((char*)hwL + r * 512 + ((c * 2) ^ SW(r))) = hv;
        }
    __syncthreads();
#pragma unroll
    for (int rt = 0; rt < 2; ++rt)
#pragma unroll
      for (int n = 0; n < 2; ++n) acc[rt][n] = (f32x4){0.f, 0.f, 0.f, 0.f};
    mm_pass((const char*)hwL, WTp_hi, w, lc, lg, acc);
#pragma unroll
    for (int rt = 0; rt < 2; ++rt)
#pragma unroll
      for (int n = 0; n < 2; ++n)
#pragma unroll
        for (int i = 0; i < 4; ++i) {
          float bmv = n ? unpk_hi(bmp[rt][i]) : unpk_lo(bmp[rt][i]);
          float act = acc[rt][n][i] + bmv;
          float e = __expf(-act);
          float u = lcg_u01(rs);
          int bit = (fmaf(u, e, u) < 1.0f) ? 1 : 0;
          if (step == KSTEPS - 1) vbits |= ((uint32_t)bit << (rt * 8 + n * 4 + i));
          int r = rt * 16 + lg * 4 + i, c = w * 32 + n * 16 + lc;
          *(unsigned short*)((char*)vmL + r * 512 + ((c * 2) ^ SW(r))) =
              bit ? (unsigned short)0x3F80 : (unsigned short)0;
        }
    __syncthreads();
  }

  // ---- stage v_data into hwL (bf16, swizzled) for the FE data pass
#pragma unroll
  for (int s = 0; s < 2; ++s) {
    int unit = s * 512 + tid;
    int r = unit >> 5, c0 = (unit & 31) * 8;
    const float* src = v_data + (size_t)(row0 + r) * 256 + c0;
    float4 a = *(const float4*)src, b = *(const float4*)(src + 4);
    s16x8 pk;
    pk[0] = (short)f2bf(a.x); pk[1] = (short)f2bf(a.y);
    pk[2] = (short)f2bf(a.z); pk[3] = (short)f2bf(a.w);
    pk[4] = (short)f2bf(b.x); pk[5] = (short)f2bf(b.y);
    pk[6] = (short)f2bf(b.z); pk[7] = (short)f2bf(b.w);
    *(s16x8*)((char*)hwL + r * 512 + ((c0 * 2) ^ SW(r))) = pk;
  }
  __syncthreads();

  // ---- free energy (hi+lo W split for accuracy)
  {
    float ws2[2];
    ws2[0] = Wsum[w * 32 + lc];
    ws2[1] = Wsum[w * 32 + 16 + lc];
    f32x4 acc[2][2];

    // model pass (vmL; st from vbits registers)
#pragma unroll
    for (int rt = 0; rt < 2; ++rt)
#pragma unroll
      for (int n = 0; n < 2; ++n) acc[rt][n] = (f32x4){0.f, 0.f, 0.f, 0.f};
    mm_pass((const char*)vmL, Wp_hi, w, lc, lg, acc);
    mm_pass((const char*)vmL, Wp_lo, w, lc, lg, acc);
#pragma unroll
    for (int rt = 0; rt < 2; ++rt)
#pragma unroll
      for (int i = 0; i < 4; ++i) {
        float sv = 0.f, sf = 0.f, st = 0.f;
        int r = rt * 16 + lg * 4 + i;
#pragma unroll
        for (int n = 0; n < 2; ++n) {
          uint32_t p2 = cmws[rt][n][i];
          float cmv = unpk_lo(p2), wsv = unpk_hi(p2);
          float vw = acc[rt][n][i];
          sv += softplusf(fmaf(vw, wsv, cmv));
          sf += softplusf(fmaf(ws2[n] - vw, wsv, cmv));
          if ((vbits >> (rt * 8 + n * 4 + i)) & 1u)
            st += n ? unpk_hi(bmp[rt][i]) : unpk_lo(bmp[rt][i]);
        }
        sv += __shfl_xor(sv, 1); sv += __shfl_xor(sv, 2); sv += __shfl_xor(sv, 4); sv += __shfl_xor(sv, 8);
        sf += __shfl_xor(sf, 1); sf += __shfl_xor(sf, 2); sf += __shfl_xor(sf, 4); sf += __shfl_xor(sf, 8);
        st += __shfl_xor(st, 1); st += __shfl_xor(st, 2); st += __shfl_xor(st, 4); st += __shfl_xor(st, 8);
        if (lc == 0) {
          atomicAdd(&red[r][3], sv);
          atomicAdd(&red[r][4], sf);
          atomicAdd(&red[r][5], st);
        }
      }

    // data pass (hwL = staged v_data)
#pragma unroll
    for (int rt = 0; rt < 2; ++rt)
#pragma unroll
      for (int n = 0; n < 2; ++n) acc[rt][n] = (f32x4){0.f, 0.f, 0.f, 0.f};
    mm_pass((const char*)hwL, Wp_hi, w, lc, lg, acc);
    mm_pass((const char*)hwL, Wp_lo, w, lc, lg, acc);
#pragma unroll
    for (int rt = 0; rt < 2; ++rt)
#pragma unroll
      for (int i = 0; i < 4; ++i) {
        float sv = 0.f, sf = 0.f, st = 0.f;
        int r = rt * 16 + lg * 4 + i;
#pragma unroll
        for (int n = 0; n < 2; ++n) {
          uint32_t p2 = cmws[rt][n][i];
          float cmv = unpk_lo(p2), wsv = unpk_hi(p2);
          float vw = acc[rt][n][i];
          sv += softplusf(fmaf(vw, wsv, cmv));
          sf += softplusf(fmaf(ws2[n] - vw, wsv, cmv));
          int c = w * 32 + n * 16 + lc;
          float xv = bf2f(*(const unsigned short*)((const char*)hwL + r * 512 + ((c * 2) ^ SW(r))));
          float bmv = n ? unpk_hi(bmp[rt][i]) : unpk_lo(bmp[rt][i]);
          st = fmaf(xv, bmv, st);
        }
        sv += __shfl_xor(sv, 1); sv += __shfl_xor(sv, 2); sv += __shfl_xor(sv, 4); sv += __shfl_xor(sv, 8);
        sf += __shfl_xor(sf, 1); sf += __shfl_xor(sf, 2); sf += __shfl_xor(sf, 4); sf += __shfl_xor(sf, 8);
        st += __shfl_xor(st, 1); st += __shfl_xor(st, 2); st += __shfl_xor(st, 4); st += __shfl_xor(st, 8);
        if (lc == 0) {
          atomicAdd(&red[r][0], sv);
          atomicAdd(&red[r][1], sf);
          atomicAdd(&red[r][2], st);
        }
      }
  }
  __syncthreads();

  if (tid < BR) {
    int r = tid;
    float a_d = red[r][2] + red[r][0];
    float b_d = (red[r][6] - red[r][2]) + red[r][1];
    float fe_d = -(fmaxf(a_d, b_d) + log1pf(expf(-fabsf(a_d - b_d))));
    float a_m = red[r][5] + red[r][3];
    float b_m = (red[r][6] - red[r][5]) + red[r][4];
    float fe_m = -(fmaxf(a_m, b_m) + log1pf(expf(-fabsf(a_m - b_m))));
    float d = fe_d - fe_m;
#pragma unroll
    for (int m = 1; m < 32; m <<= 1) d += __shfl_xor(d, m);
    if (tid == 0) atomicAdd(out, d * (1.0f / (float)Btot));
  }
}

// ---------------- launch --------------------------------------------------
extern "C" void kernel_launch(void* const* d_in, const int* in_sizes, int n_in,
                              void* d_out, int out_size, void* d_ws, size_t ws_size,
                              hipStream_t stream) {
  const float* v_data = (const float*)d_in[0];
  const float* cond = (const float*)d_in[1];
  const float* W = (const float*)d_in[2];
  const float* bvec = (const float*)d_in[3];
  const float* cvec = (const float*)d_in[4];
  const float* fc1_w = (const float*)d_in[5];
  const float* fc1_b = (const float*)d_in[6];
  const float* fc2_w = (const float*)d_in[7];
  const float* fc2_b = (const float*)d_in[8];
  float* out = (float*)d_out;

  int Btot = in_sizes[0] / V;              // 32768
  int nnoise = (int)((double)Btot * 0.1);  // 3276

  // ws (shorts): Wp_hi[65536] | Wp_lo[65536] | WTp_hi[65536] | fc2p[81920] | Wsum f32[256]
  unsigned short* Wp_hi = (unsigned short*)d_ws;
  unsigned short* Wp_lo = Wp_hi + 65536;
  unsigned short* WTp_hi = Wp_lo + 65536;
  unsigned short* fc2p = WTp_hi + 65536;
  float* Wsum = (float*)(fc2p + 81920);

  k_prep<<<577, 256, 0, stream>>>(W, fc2_w, Wp_hi, Wp_lo, WTp_hi, fc2p, Wsum, out);
  rbm_mfma<<<Btot / BR, 512, 0, stream>>>(v_data, cond, bvec, cvec, fc1_w, fc1_b, fc2_b,
                                          Wp_hi, Wp_lo, WTp_hi, fc2p, Wsum, out, Btot, nnoise);
}

// Round 9
// 402.450 us; speedup vs baseline: 1.7554x; 1.1648x over previous
//
#include <hip/hip_runtime.h>
#include <stdint.h>

#define V 256
#define H 256
#define CONDD 64
#define WIDTH 64
#define KSTEPS 5
#define BR 16
#define GWMAX 0.05f
// Swizzle for 512B-row LDS tiles: XOR byte bits[7:4] with row bits[3:0].
// Verified round 5/8: SQ_LDS_BANK_CONFLICT 9.5M -> 32K (free).
#define SW(r) (((r) & 15) << 4)
// xS rows are 128B; 8-granule space, XOR row bits[2:0].
#define SWX(r) (((r) & 7) << 4)

typedef __attribute__((ext_vector_type(8))) short s16x8;
typedef __attribute__((ext_vector_type(4))) float f32x4;

__device__ __forceinline__ uint64_t splitmix64(uint64_t x) {
  x += 0x9E3779B97F4A7C15ULL;
  x = (x ^ (x >> 30)) * 0xBF58476D1CE4E5B9ULL;
  x = (x ^ (x >> 27)) * 0x94D049BB133111EBULL;
  return x ^ (x >> 31);
}
__device__ __forceinline__ unsigned short f2bf(float f) {
  uint32_t u = __float_as_uint(f);
  return (unsigned short)((u + 0x7FFFu + ((u >> 16) & 1u)) >> 16);
}
__device__ __forceinline__ float bf2f(unsigned short s) {
  return __uint_as_float(((uint32_t)s) << 16);
}
__device__ __forceinline__ uint32_t pack2(float lo, float hi) {
  return (uint32_t)f2bf(lo) | ((uint32_t)f2bf(hi) << 16);
}
__device__ __forceinline__ float unpk_lo(uint32_t u) { return bf2f((unsigned short)(u & 0xFFFFu)); }
__device__ __forceinline__ float unpk_hi(uint32_t u) { return bf2f((unsigned short)(u >> 16)); }
// fast transcendentals (err ~1e-6, threshold is 0.78 -> irrelevant)
__device__ __forceinline__ float fast_sp(float x) {  // softplus
  return fmaxf(x, 0.0f) + __logf(1.0f + __expf(-fabsf(x)));
}
__device__ __forceinline__ float fast_tanh(float x) {
  float t = __expf(-2.0f * fabsf(x));            // in (0,1], no overflow
  float r = (1.0f - t) * __builtin_amdgcn_rcpf(1.0f + t);
  return copysignf(r, x);
}

// ---------------- merged prep kernel (1 launch) ---------------------------
__global__ void k_prep(const float* __restrict__ W, const float* __restrict__ fc2_w,
                       unsigned short* __restrict__ Wp_hi, unsigned short* __restrict__ Wp_lo,
                       unsigned short* __restrict__ WTp_hi, unsigned short* __restrict__ fc2p,
                       float* __restrict__ Wsum, float* __restrict__ out) {
  int bid = blockIdx.x;
  if (bid < 256) {
    int idx = bid * 256 + threadIdx.x;  // 65536
    int j = idx & 7, l = (idx >> 3) & 63, nt = (idx >> 9) & 15, ks = idx >> 13;
    int kk = ks * 32 + (l >> 4) * 8 + j;
    int n = nt * 16 + (l & 15);
    float wv = W[(size_t)kk * H + n];           // B = W (k=v, n=h)
    unsigned short hi = f2bf(wv);
    Wp_hi[idx] = hi;
    Wp_lo[idx] = f2bf(wv - bf2f(hi));
    WTp_hi[idx] = f2bf(W[(size_t)n * H + kk]);  // B = W^T (k=h, n=v)
  } else if (bid < 576) {
    int idx = (bid - 256) * 256 + threadIdx.x;  // 81920
    int j = idx & 7, l = (idx >> 3) & 63;
    int f = idx >> 9;  // 0..159
    int ks = f / 80, nt = f % 80;
    fc2p[idx] = f2bf(fc2_w[(size_t)(nt * 16 + (l & 15)) * WIDTH + ks * 32 + (l >> 4) * 8 + j]);
  } else {
    int h = threadIdx.x;
    float s = 0.f;
    for (int v = 0; v < V; ++v) s += W[(size_t)v * H + h];
    Wsum[h] = s;
    if (h == 0) out[0] = 0.0f;  // d_out is poisoned 0xAA before every launch
  }
}

// ---------------- MFMA tile pass: 1 row-tile (16 rows), 2 n-tiles ---------
// wave w owns rows [0,16) x cols [w*32, w*32+32); acc[2] = 8 VGPRs.
__device__ __forceinline__ void mm_pass(const char* srcL, const unsigned short* __restrict__ Wp,
                                        int w, int lc, int lg, f32x4 acc[2]) {
#pragma unroll
  for (int ks = 0; ks < 8; ++ks) {
    s16x8 af = *(const s16x8*)(srcL + lc * 512 + ((ks * 64 + lg * 16) ^ SW(lc)));
#pragma unroll
    for (int n = 0; n < 2; ++n) {
      int f = ks * 16 + 2 * w + n;
      s16x8 bf = *(const s16x8*)(Wp + ((size_t)f * 64 + lg * 16 + lc) * 8);
      acc[n] = __builtin_amdgcn_mfma_f32_16x16x32_bf16(af, bf, acc[n], 0, 0, 0);
    }
  }
}

// one fc2 output slice into acc[2]
__device__ __forceinline__ void fc2_slice(const s16x8 afx[2],
                                          const unsigned short* __restrict__ fc2p,
                                          int w, int l, int slice, f32x4 acc[2]) {
#pragma unroll
  for (int n = 0; n < 2; ++n) acc[n] = (f32x4){0.f, 0.f, 0.f, 0.f};
#pragma unroll
  for (int ks = 0; ks < 2; ++ks)
#pragma unroll
    for (int n = 0; n < 2; ++n) {
      int f = ks * 80 + slice * 16 + 2 * w + n;
      s16x8 bf = *(const s16x8*)(fc2p + ((size_t)f * 64 + l) * 8);
      acc[n] = __builtin_amdgcn_mfma_f32_16x16x32_bf16(afx[ks], bf, acc[n], 0, 0, 0);
    }
}

// ---------------- fused main kernel --------------------------------------
__global__ __launch_bounds__(512) void rbm_mfma(
    const float* __restrict__ v_data, const float* __restrict__ cond,
    const float* __restrict__ bvec, const float* __restrict__ cvec,
    const float* __restrict__ fc1_w, const float* __restrict__ fc1_b,
    const float* __restrict__ fc2_b, const unsigned short* __restrict__ Wp_hi,
    const unsigned short* __restrict__ Wp_lo, const unsigned short* __restrict__ WTp_hi,
    const unsigned short* __restrict__ fc2p, const float* __restrict__ Wsum,
    float* __restrict__ out, int Btot, int nnoise) {
  const int tid = threadIdx.x;
  const int w = tid >> 6, l = tid & 63, lc = l & 15, lg = l >> 4;
  const int row0 = blockIdx.x * BR;

  __shared__ unsigned short vmL[BR * 256];  // v_model bf16, swizzled 512B rows (8 KB)
  __shared__ unsigned short hwL[BR * 256];  // h*wsc; early: cond+x overlay; late: v_data
  __shared__ float red[BR][8];

  if (tid < BR * 8) ((float*)red)[tid] = 0.0f;

  float* condS = (float*)hwL;            // [16][68] f32 = 4352 B
  char* xS = (char*)hwL + BR * 68 * 4;   // 16 rows x 128 B bf16 (SWX swizzle)

  // ---- stage cond (coalesced; 16x64 = 1024 floats)
#pragma unroll
  for (int s = 0; s < 2; ++s) {
    int e = s * 512 + tid, r = e >> 6, k = e & 63;
    condS[r * 68 + k] = cond[(size_t)(row0 + r) * CONDD + k];
  }
  // ---- stage v_model (bf16, swizzled; first nnoise rows = Bernoulli(0.5))
  {
    int r = tid >> 5, c0 = (tid & 31) * 8;
    int g = row0 + r;
    s16x8 pk;
    if (g < nnoise) {
      uint32_t bits = (uint32_t)(splitmix64(((uint64_t)g << 6) | (uint64_t)(c0 >> 3)) >> 32);
#pragma unroll
      for (int j = 0; j < 8; ++j) pk[j] = (short)(((bits >> j) & 1u) ? 0x3F80 : 0);
    } else {
      const float* src = v_data + (size_t)g * 256 + c0;
      float4 a = *(const float4*)src, b = *(const float4*)(src + 4);
      pk[0] = (short)f2bf(a.x); pk[1] = (short)f2bf(a.y);
      pk[2] = (short)f2bf(a.z); pk[3] = (short)f2bf(a.w);
      pk[4] = (short)f2bf(b.x); pk[5] = (short)f2bf(b.y);
      pk[6] = (short)f2bf(b.z); pk[7] = (short)f2bf(b.w);
    }
    *(s16x8*)((char*)vmL + r * 512 + ((c0 * 2) ^ SW(r))) = pk;
  }
  __syncthreads();

  // ---- fc1: x = tanh(cond @ fc1_w^T + fc1_b); 2 outputs/thread
  {
    int r = tid >> 5, j0 = (tid & 31) * 2;
    float a0 = fc1_b[j0], a1 = fc1_b[j0 + 1];
    for (int k = 0; k < CONDD; ++k) {
      float cv = condS[r * 68 + k];
      a0 = fmaf(cv, fc1_w[(size_t)j0 * CONDD + k], a0);
      a1 = fmaf(cv, fc1_w[(size_t)(j0 + 1) * CONDD + k], a1);
    }
    uint32_t xp = pack2(fast_tanh(a0), fast_tanh(a1));
    *(uint32_t*)(xS + r * 128 + ((j0 * 2) ^ SWX(r))) = xp;
  }
  __syncthreads();

  // ---- fc2 via MFMA, bf16-packed params: cmws = (cm | ws<<16), bmp = (bm_n0 | bm_n1<<16)
  uint32_t cmws[2][4];  // 8 VGPRs
  uint32_t bmp[4];      // 4 VGPRs
  {
    s16x8 afx[2];
#pragma unroll
    for (int ks = 0; ks < 2; ++ks)
      afx[ks] = *(const s16x8*)(xS + lc * 128 + (((ks * 32 + lg * 8) * 2) ^ SWX(lc)));
    f32x4 accA[2], accB[2];
    fc2_slice(afx, fc2p, w, l, 0, accA);  // gb
    fc2_slice(afx, fc2p, w, l, 1, accB);  // bb
    {
      int c0 = w * 32 + lc, c1 = c0 + 16;
      float f00 = fc2_b[c0], f01 = fc2_b[c1], f10 = fc2_b[V + c0], f11 = fc2_b[V + c1];
      float bv0 = bvec[c0], bv1 = bvec[c1];
#pragma unroll
      for (int i = 0; i < 4; ++i)
        bmp[i] = pack2(fmaf(1.0f + (accA[0][i] + f00), bv0, accB[0][i] + f10),
                       fmaf(1.0f + (accA[1][i] + f01), bv1, accB[1][i] + f11));
    }
    fc2_slice(afx, fc2p, w, l, 2, accA);  // gc
    fc2_slice(afx, fc2p, w, l, 3, accB);  // bc
#pragma unroll
    for (int n = 0; n < 2; ++n) {
      int col = w * 32 + n * 16 + lc;
      float fb2 = fc2_b[2 * V + col], fb3 = fc2_b[2 * V + H + col], cv = cvec[col];
#pragma unroll
      for (int i = 0; i < 4; ++i)
        accB[n][i] = fmaf(1.0f + (accA[n][i] + fb2), cv, accB[n][i] + fb3);
    }
    fc2_slice(afx, fc2p, w, l, 4, accA);  // gw
#pragma unroll
    for (int n = 0; n < 2; ++n) {
      int col = w * 32 + n * 16 + lc;
      float fb4 = fc2_b[2 * V + 2 * H + col];
#pragma unroll
      for (int i = 0; i < 4; ++i)
        cmws[n][i] = pack2(accB[n][i], 1.0f + GWMAX * fast_tanh(accA[n][i] + fb4));
    }
  }
  // Sb = sum_v bm[r][v]
#pragma unroll
  for (int i = 0; i < 4; ++i) {
    float s = unpk_lo(bmp[i]) + unpk_hi(bmp[i]);
    s += __shfl_xor(s, 1); s += __shfl_xor(s, 2);
    s += __shfl_xor(s, 4); s += __shfl_xor(s, 8);
    if (lc == 0) atomicAdd(&red[lg * 4 + i][6], s);
  }
  __syncthreads();  // x/cond reads done; hwL free for h-samples

  // ---- Gibbs chain; 32-bit LCG, final v-samples in 8-bit register mask
  uint32_t r32 = (uint32_t)splitmix64(0xBEEF000000000000ULL | (uint64_t)(blockIdx.x * 512 + tid));
  uint32_t vbits = 0;
  for (int step = 0; step < KSTEPS; ++step) {
    f32x4 acc[2];
#pragma unroll
    for (int n = 0; n < 2; ++n) acc[n] = (f32x4){0.f, 0.f, 0.f, 0.f};
    mm_pass((const char*)vmL, Wp_hi, w, lc, lg, acc);
#pragma unroll
    for (int n = 0; n < 2; ++n)
#pragma unroll
      for (int i = 0; i < 4; ++i) {
        uint32_t p2 = cmws[n][i];
        float act = fmaf(acc[n][i], unpk_hi(p2), unpk_lo(p2));
        float e = __expf(-act);
        r32 = r32 * 1664525u + 1013904223u;
        float u = (float)(r32 >> 8) * (1.0f / 16777216.0f);
        unsigned short hv = (fmaf(u, e, u) < 1.0f) ? (unsigned short)(p2 >> 16)
                                                   : (unsigned short)0;
        int r = lg * 4 + i, c = w * 32 + n * 16 + lc;
        *(unsigned short*)((char*)hwL + r * 512 + ((c * 2) ^ SW(r))) = hv;
      }
    __syncthreads();
#pragma unroll
    for (int n = 0; n < 2; ++n) acc[n] = (f32x4){0.f, 0.f, 0.f, 0.f};
    mm_pass((const char*)hwL, WTp_hi, w, lc, lg, acc);
#pragma unroll
    for (int n = 0; n < 2; ++n)
#pragma unroll
      for (int i = 0; i < 4; ++i) {
        float bmv = n ? unpk_hi(bmp[i]) : unpk_lo(bmp[i]);
        float act = acc[n][i] + bmv;
        float e = __expf(-act);
        r32 = r32 * 1664525u + 1013904223u;
        float u = (float)(r32 >> 8) * (1.0f / 16777216.0f);
        int bit = (fmaf(u, e, u) < 1.0f) ? 1 : 0;
        if (step == KSTEPS - 1) vbits |= ((uint32_t)bit << (n * 4 + i));
        int r = lg * 4 + i, c = w * 32 + n * 16 + lc;
        *(unsigned short*)((char*)vmL + r * 512 + ((c * 2) ^ SW(r))) =
            bit ? (unsigned short)0x3F80 : (unsigned short)0;
      }
    __syncthreads();
  }

  // ---- stage v_data into hwL (independent of vmL model pass below)
  {
    int r = tid >> 5, c0 = (tid & 31) * 8;
    const float* src = v_data + (size_t)(row0 + r) * 256 + c0;
    float4 a = *(const float4*)src, b = *(const float4*)(src + 4);
    s16x8 pk;
    pk[0] = (short)f2bf(a.x); pk[1] = (short)f2bf(a.y);
    pk[2] = (short)f2bf(a.z); pk[3] = (short)f2bf(a.w);
    pk[4] = (short)f2bf(b.x); pk[5] = (short)f2bf(b.y);
    pk[6] = (short)f2bf(b.z); pk[7] = (short)f2bf(b.w);
    *(s16x8*)((char*)hwL + r * 512 + ((c0 * 2) ^ SW(r))) = pk;
  }

  // ---- free energy (hi+lo W split for accuracy)
  {
    float ws2[2];
    ws2[0] = Wsum[w * 32 + lc];
    ws2[1] = Wsum[w * 32 + 16 + lc];
    f32x4 acc[2];

    // model pass (vmL; st from vbits registers)
#pragma unroll
    for (int n = 0; n < 2; ++n) acc[n] = (f32x4){0.f, 0.f, 0.f, 0.f};
    mm_pass((const char*)vmL, Wp_hi, w, lc, lg, acc);
    mm_pass((const char*)vmL, Wp_lo, w, lc, lg, acc);
#pragma unroll
    for (int i = 0; i < 4; ++i) {
      float sv = 0.f, sf = 0.f, st = 0.f;
      int r = lg * 4 + i;
#pragma unroll
      for (int n = 0; n < 2; ++n) {
        uint32_t p2 = cmws[n][i];
        float cmv = unpk_lo(p2), wsv = unpk_hi(p2);
        float vw = acc[n][i];
        sv += fast_sp(fmaf(vw, wsv, cmv));
        sf += fast_sp(fmaf(ws2[n] - vw, wsv, cmv));
        if ((vbits >> (n * 4 + i)) & 1u) st += n ? unpk_hi(bmp[i]) : unpk_lo(bmp[i]);
      }
      sv += __shfl_xor(sv, 1); sv += __shfl_xor(sv, 2); sv += __shfl_xor(sv, 4); sv += __shfl_xor(sv, 8);
      sf += __shfl_xor(sf, 1); sf += __shfl_xor(sf, 2); sf += __shfl_xor(sf, 4); sf += __shfl_xor(sf, 8);
      st += __shfl_xor(st, 1); st += __shfl_xor(st, 2); st += __shfl_xor(st, 4); st += __shfl_xor(st, 8);
      if (lc == 0) {
        atomicAdd(&red[r][3], sv);
        atomicAdd(&red[r][4], sf);
        atomicAdd(&red[r][5], st);
      }
    }
    __syncthreads();  // v_data staged + model pass done

    // data pass (hwL = staged v_data)
#pragma unroll
    for (int n = 0; n < 2; ++n) acc[n] = (f32x4){0.f, 0.f, 0.f, 0.f};
    mm_pass((const char*)hwL, Wp_hi, w, lc, lg, acc);
    mm_pass((const char*)hwL, Wp_lo, w, lc, lg, acc);
#pragma unroll
    for (int i = 0; i < 4; ++i) {
      float sv = 0.f, sf = 0.f, st = 0.f;
      int r = lg * 4 + i;
#pragma unroll
      for (int n = 0; n < 2; ++n) {
        uint32_t p2 = cmws[n][i];
        float cmv = unpk_lo(p2), wsv = unpk_hi(p2);
        float vw = acc[n][i];
        sv += fast_sp(fmaf(vw, wsv, cmv));
        sf += fast_sp(fmaf(ws2[n] - vw, wsv, cmv));
        int c = w * 32 + n * 16 + lc;
        float xv = bf2f(*(const unsigned short*)((const char*)hwL + r * 512 + ((c * 2) ^ SW(r))));
        float bmv = n ? unpk_hi(bmp[i]) : unpk_lo(bmp[i]);
        st = fmaf(xv, bmv, st);
      }
      sv += __shfl_xor(sv, 1); sv += __shfl_xor(sv, 2); sv += __shfl_xor(sv, 4); sv += __shfl_xor(sv, 8);
      sf += __shfl_xor(sf, 1); sf += __shfl_xor(sf, 2); sf += __shfl_xor(sf, 4); sf += __shfl_xor(sf, 8);
      st += __shfl_xor(st, 1); st += __shfl_xor(st, 2); st += __shfl_xor(st, 4); st += __shfl_xor(st, 8);
      if (lc == 0) {
        atomicAdd(&red[r][0], sv);
        atomicAdd(&red[r][1], sf);
        atomicAdd(&red[r][2], st);
      }
    }
  }
  __syncthreads();

  if (tid < BR) {
    int r = tid;
    float a_d = red[r][2] + red[r][0];
    float b_d = (red[r][6] - red[r][2]) + red[r][1];
    float fe_d = -(fmaxf(a_d, b_d) + log1pf(expf(-fabsf(a_d - b_d))));
    float a_m = red[r][5] + red[r][3];
    float b_m = (red[r][6] - red[r][5]) + red[r][4];
    float fe_m = -(fmaxf(a_m, b_m) + log1pf(expf(-fabsf(a_m - b_m))));
    float d = fe_d - fe_m;
#pragma unroll
    for (int m = 1; m < 16; m <<= 1) d += __shfl_xor(d, m);
    if (tid == 0) atomicAdd(out, d * (1.0f / (float)Btot));
  }
}

// ---------------- launch --------------------------------------------------
extern "C" void kernel_launch(void* const* d_in, const int* in_sizes, int n_in,
                              void* d_out, int out_size, void* d_ws, size_t ws_size,
                              hipStream_t stream) {
  const float* v_data = (const float*)d_in[0];
  const float* cond = (const float*)d_in[1];
  const float* W = (const float*)d_in[2];
  const float* bvec = (const float*)d_in[3];
  const float* cvec = (const float*)d_in[4];
  const float* fc1_w = (const float*)d_in[5];
  const float* fc1_b = (const float*)d_in[6];
  const float* fc2_w = (const float*)d_in[7];
  const float* fc2_b = (const float*)d_in[8];
  float* out = (float*)d_out;

  int Btot = in_sizes[0] / V;              // 32768
  int nnoise = (int)((double)Btot * 0.1);  // 3276

  // ws (shorts): Wp_hi[65536] | Wp_lo[65536] | WTp_hi[65536] | fc2p[81920] | Wsum f32[256]
  unsigned short* Wp_hi = (unsigned short*)d_ws;
  unsigned short* Wp_lo = Wp_hi + 65536;
  unsigned short* WTp_hi = Wp_lo + 65536;
  unsigned short* fc2p = WTp_hi + 65536;
  float* Wsum = (float*)(fc2p + 81920);

  k_prep<<<577, 256, 0, stream>>>(W, fc2_w, Wp_hi, Wp_lo, WTp_hi, fc2p, Wsum, out);
  rbm_mfma<<<Btot / BR, 512, 0, stream>>>(v_data, cond, bvec, cvec, fc1_w, fc1_b, fc2_b,
                                          Wp_hi, Wp_lo, WTp_hi, fc2p, Wsum, out, Btot, nnoise);
}